// Round 12
// baseline (110.793 us; speedup 1.0000x reference)
//
#include <hip/hip_runtime.h>
#include <hip/hip_bf16.h>

// MPS log-trace: out[b] = log(trace(prod_{n=0..1023} A[s_idx[b,n]]))
//   Kernel 1: 256-entry table T[key] = A[b0]@...@A[b7] (fp32 in LDS), stored
//             bf16 as MFMA A-fragments with SIGMA-PERMUTED k-slots (R7-proven).
//   Kernel 2: QUARTER-split chain, 1 batch per 256-thread block, grid 4096,
//             __launch_bounds__(256,8) targeting <=64 VGPR / 8 waves per SIMD
//             (R10 PMC: 33% occupancy, both pipes <28% -> TLP-bound).
//             Combine (R11 bug fixed): waves 1/3 export Q^T to LDS as f32 in the
//             ROTATED layout Qt[x*32+((y+x)&31)] = Q^T[x][y] (the LDS scatter IS
//             the lane<->register transpose that R11's in-register export
//             skipped); waves 0/2 read Q^T[col][sg] + cvt_pk -> A operand, one
//             extra MFMA step -> R^T,S^T; then R6-proven rotated-Ht trace dot.
// Ledger: launch_bounds exonerated (R9). readfirstlane & z-hoist quarantined.

#define BATCH   4096
#define N_SITES 1024
#define NKEYS   256
#define NSTEP_Q 32    // steps per wave (quarter chain)

typedef __attribute__((ext_vector_type(8)))  short    short8;
typedef __attribute__((ext_vector_type(16))) float    f32x16;
typedef __attribute__((ext_vector_type(4)))  unsigned uint4v;

// f32 -> bf16 RNE, bit-op version (table-build tail only)
static __device__ __forceinline__ unsigned short f32_to_bf16(float f) {
  unsigned u = __builtin_bit_cast(unsigned, f);
  const unsigned rounding = 0x7FFFu + ((u >> 16) & 1u);
  return (unsigned short)((u + rounding) >> 16);
}

// packed f32x2 -> bf16x2 in one VALU instruction (RNE; src0 -> low 16)
static __device__ __forceinline__ unsigned cvt_pk_bf16(float lo, float hi) {
  unsigned r;
  asm("v_cvt_pk_bf16_f32 %0, %1, %2" : "=v"(r) : "v"(lo), "v"(hi));
  return r;
}

// ---------------------------------------------------------------------------
// Kernel 1: table build. 256 blocks (one per key) x 256 threads. (R7-proven)
// ---------------------------------------------------------------------------
__global__ __launch_bounds__(256) void build_table_k(const float* __restrict__ A,
                                                     unsigned short* __restrict__ table) {
  __shared__ float As[2][32][32];
  __shared__ float M[2][32][32];
  const int key = blockIdx.x;
  const int t   = threadIdx.x;

  for (int i = t; i < 2 * 32 * 32; i += 256) ((float*)As)[i] = A[i];

  const int row = t >> 3;          // 0..31
  const int col = (t & 7) << 2;    // 0,4,...,28
  __syncthreads();

  {
    const int b0 = key & 1;
    const float4 v = *reinterpret_cast<const float4*>(&As[b0][row][col]);
    *reinterpret_cast<float4*>(&M[0][row][col]) = v;
  }
  __syncthreads();

  int cur = 0;
  for (int i = 1; i < 8; ++i) {
    const int bi = (key >> i) & 1;
    float a0 = 0.f, a1 = 0.f, a2 = 0.f, a3 = 0.f;
    for (int k = 0; k < 32; ++k) {
      const float m  = M[cur][row][k];
      const float4 v = *reinterpret_cast<const float4*>(&As[bi][k][col]);
      a0 += m * v.x; a1 += m * v.y; a2 += m * v.z; a3 += m * v.w;
    }
    M[cur ^ 1][row][col + 0] = a0;
    M[cur ^ 1][row][col + 1] = a1;
    M[cur ^ 1][row][col + 2] = a2;
    M[cur ^ 1][row][col + 3] = a3;
    __syncthreads();
    cur ^= 1;
  }

  // bf16 entry, A-fragment layout of T^T with sigma-permuted k-slots:
  //   MFMA c, lane l (rowm=l&31, hi=l>>5), elem ee=0..7:
  //     sg = (ee&3) + 8*(ee>>2) + 4*hi + 16*c ;  value = T[sg][rowm]
  const int c    = t >> 7;         // 0..1
  const int l    = (t >> 1) & 63;  // lane
  const int e4   = (t & 1) << 2;   // 0 or 4
  const int rowm = l & 31;
  const int hi   = l >> 5;

  unsigned long long packed = 0;
  for (int e = 0; e < 4; ++e) {
    const int ee = e4 + e;
    const int sg = (ee & 3) + ((ee >> 2) << 3) + (hi << 2) + (c << 4);
    const unsigned short us = f32_to_bf16(M[cur][sg][rowm]);
    packed |= (unsigned long long)us << (16 * e);
  }
  *reinterpret_cast<unsigned long long*>(table + (size_t)key * 1024 + c * 512 + l * 8 + e4) = packed;
}

// ---------------------------------------------------------------------------
// Kernel 2: quarter-split chain. 4096 blocks x 256 threads (4 waves = 1 batch).
// Wave q handles steps [32q, 32q+32).
// ---------------------------------------------------------------------------
__global__ __launch_bounds__(256, 8) void mps_chain_k(const float* __restrict__ s,
                                                      const unsigned short* __restrict__ table,
                                                      float* __restrict__ out) {
  const int t    = threadIdx.x;
  const int wv   = t >> 6;          // quarter index 0..3
  const int lane = t & 63;
  const int b    = blockIdx.x;

  __shared__ unsigned char keys[136];  // 128 keys + pad
  __shared__ float Qt1[1024];          // Q1^T, rotated: Qt[x*32+((y+x)&31)] = Q1^T[x][y]
  __shared__ float Qt3[1024];          // Q3^T, same layout
  __shared__ float Ht[1024];           // S^T rotated (R6 layout) for trace dot

  // --- key extraction: thread t<128 computes key t (32B coalesced reads)
  if (t < 128) {
    const float4* s4 = reinterpret_cast<const float4*>(s) + (size_t)b * 256 + t * 2;
    const float4 va = s4[0];
    const float4 vb = s4[1];
    keys[t] =
        (unsigned char)((va.x > 0.f ? 1u : 0u)  | (va.y > 0.f ? 2u : 0u)  |
                        (va.z > 0.f ? 4u : 0u)  | (va.w > 0.f ? 8u : 0u)  |
                        (vb.x > 0.f ? 16u : 0u) | (vb.y > 0.f ? 32u : 0u) |
                        (vb.z > 0.f ? 64u : 0u) | (vb.w > 0.f ? 128u : 0u));
  } else if (t < 136) {
    keys[t] = 0;                       // pad
  }
  __syncthreads();

  const int col = lane & 31;
  const int hi  = lane >> 5;

  // carry = I in 32x32 C-layout: acc[r] = M[(r&3)+8*(r>>2)+4*hi][col]
  f32x16 acc;
#pragma unroll
  for (int r = 0; r < 16; ++r) {
    const int rr = (r & 3) + 8 * (r >> 2) + 4 * hi;
    acc[r] = (rr == col) ? 1.f : 0.f;
  }

  const unsigned char* kw = keys + wv * NSTEP_Q;
  const unsigned long long laneoff = (unsigned long long)lane * 8;

  // 1-deep fragment prefetch
  const unsigned short* e0 = table + ((size_t)kw[0] << 10);
  uint4v c0 = *reinterpret_cast<const uint4v*>(e0 + laneoff);
  uint4v c1 = *reinterpret_cast<const uint4v*>(e0 + 512 + laneoff);
  unsigned kN = kw[1];

#pragma unroll 2
  for (int j = 0; j < NSTEP_Q; ++j) {
    // issue loads for step j+1
    const unsigned short* ef = table + ((size_t)kN << 10);
    const uint4v f0 = *reinterpret_cast<const uint4v*>(ef + laneoff);
    const uint4v f1 = *reinterpret_cast<const uint4v*>(ef + 512 + laneoff);
    kN = kw[j + 2];                    // pad keeps tail reads in-bounds

    f32x16 z;
#pragma unroll
    for (int r = 0; r < 16; ++r) z[r] = 0.f;

    // acc -> bf16 B fragments (direct pairing via sigma table), 8 cvt_pk
    union { unsigned u[4]; short8 v; } B1, B2;
#pragma unroll
    for (int i = 0; i < 4; ++i) {
      B1.u[i] = cvt_pk_bf16(acc[2 * i],     acc[2 * i + 1]);
      B2.u[i] = cvt_pk_bf16(acc[8 + 2 * i], acc[9 + 2 * i]);
    }

    union { uint4v q; short8 v; } u0, u1;
    u0.q = c0; u1.q = c1;

    f32x16 t1 = __builtin_amdgcn_mfma_f32_32x32x16_bf16(u0.v, B1.v, z, 0, 0, 0);
    acc = __builtin_amdgcn_mfma_f32_32x32x16_bf16(u1.v, B2.v, t1, 0, 0, 0);

    // rotate pipeline
    c0 = f0; c1 = f1;
  }

  // --- combine. P = Q0 Q1 Q2 Q3; R = Q0Q1 (wave0), S = Q2Q3 (wave2);
  // trace(P) = trace(R S) = sum_{i,k} R[i,k] S[k,i].
  // Waves 1/3: export acc (= Q^T in C-layout) to rotated f32 LDS.
  // Element Q^T[x=row_C(r)][y=col] -> Qt[x*32 + ((y+x)&31)].
  // (write: 32 lanes per hi-group hit distinct banks; 2 hi-groups = 2-way, free)
  if (wv == 1 || wv == 3) {
    float* qp = (wv == 1) ? Qt1 : Qt3;
#pragma unroll
    for (int r = 0; r < 16; ++r) {
      const int x = (r & 3) + 8 * (r >> 2) + 4 * hi;
      qp[x * 32 + ((col + x) & 31)] = acc[r];
    }
  }
  __syncthreads();

  if (wv == 0 || wv == 2) {
    // one more sigma-step: acc <- Qhat^T @ acc  (Qhat = Q1 for wv0, Q3 for wv2).
    // A-frag halfword (c,lane,e) needs Qhat^T[col][sg], sg=(e&3)+8*(e>>2)+4*hi+16*c,
    // read from rotated LDS at Qt[col*32 + ((sg+col)&31)].
    const float* qp = (wv == 0) ? Qt1 : Qt3;
    union { unsigned u[4]; short8 v; } A1, A2;
#pragma unroll
    for (int i = 0; i < 4; ++i) {
      const int e0i = 2 * i, e1i = 2 * i + 1;
      const int sgA = (e0i & 3) + 8 * (e0i >> 2) + 4 * hi;
      const int sgB = (e1i & 3) + 8 * (e1i >> 2) + 4 * hi;
      A1.u[i] = cvt_pk_bf16(qp[col * 32 + ((sgA + col) & 31)],
                            qp[col * 32 + ((sgB + col) & 31)]);
      A2.u[i] = cvt_pk_bf16(qp[col * 32 + (((sgA + 16) + col) & 31)],
                            qp[col * 32 + (((sgB + 16) + col) & 31)]);
    }

    union { unsigned u[4]; short8 v; } B1, B2;
#pragma unroll
    for (int i = 0; i < 4; ++i) {
      B1.u[i] = cvt_pk_bf16(acc[2 * i],     acc[2 * i + 1]);
      B2.u[i] = cvt_pk_bf16(acc[8 + 2 * i], acc[9 + 2 * i]);
    }

    f32x16 z;
#pragma unroll
    for (int r = 0; r < 16; ++r) z[r] = 0.f;

    f32x16 t1 = __builtin_amdgcn_mfma_f32_32x32x16_bf16(A1.v, B1.v, z, 0, 0, 0);
    acc = __builtin_amdgcn_mfma_f32_32x32x16_bf16(A2.v, B2.v, t1, 0, 0, 0);
    // wave0: acc = R^T = Q1^T@Q0^T ; wave2: acc = S^T = Q3^T@Q2^T
  }

  // wave2 stores S^T via rotated transpose (R6-proven trace combine).
  if (wv == 2) {
#pragma unroll
    for (int r = 0; r < 16; ++r) {
      const int a = (r & 3) + 8 * (r >> 2) + 4 * hi;
      Ht[col * 32 + ((a + col) & 31)] = acc[r];
    }
  }
  __syncthreads();
  if (wv == 0) {
    float dot = 0.f;
#pragma unroll
    for (int r = 0; r < 16; ++r) {
      const int k = (r & 3) + 8 * (r >> 2) + 4 * hi;   // R^T row index
      dot += acc[r] * Ht[k * 32 + ((col + k) & 31)];
    }
#pragma unroll
    for (int off = 32; off > 0; off >>= 1) dot += __shfl_down(dot, off, 64);
    if (lane == 0) out[b] = logf(dot);
  }
}

// ---------------------------------------------------------------------------
extern "C" void kernel_launch(void* const* d_in, const int* in_sizes, int n_in,
                              void* d_out, int out_size, void* d_ws, size_t ws_size,
                              hipStream_t stream) {
  const float* s = (const float*)d_in[0];   // [4096,1024] f32
  const float* A = (const float*)d_in[1];   // [2,32,32] f32
  float* out = (float*)d_out;               // [4096] f32
  unsigned short* table = (unsigned short*)d_ws;  // 256 * 2048 B = 512 KiB

  build_table_k<<<NKEYS, 256, 0, stream>>>(A, table);
  mps_chain_k<<<BATCH, 256, 0, stream>>>(s, table, out);
}